// Round 3
// baseline (99.353 us; speedup 1.0000x reference)
//
#include <hip/hip_runtime.h>
#include <float.h>
#include <math.h>

#define Ln 2048
#define Bn 64
#define Cn 512
#define Qn 512
#define Vn 512
#define NO 1536   // C*KW

// workspace layout (in floats)
#define OFF_KERN 0                               // [3][B][C]  = 98304
#define OFF_ABT  98304                           // aBT[b][t]  = 131072
#define OFF_ET   (98304 + 131072)                // eT[b][t]   = 131072
#define OFF_STAT (98304 + 131072 + 131072)       // [B][2]     = 128
#define OFF_SCR  (98304 + 131072 + 131072 + 128) // gemm partials (393216) / v partials (262144)

typedef float f4 __attribute__((ext_vector_type(4)));
typedef float f2 __attribute__((ext_vector_type(2)));

__device__ __forceinline__ float dot8(f4 a0, f4 a1, f4 b0, f4 b1) {
    f4 p = a0 * b0;
    p += a1 * b1;
    return (p.x + p.y) + (p.z + p.w);
}

// ---------------- K1: kernel_flat partial GEMM  gpart[ks][b][o] = sum_k q[b,k] W[o,k]
__global__ __launch_bounds__(256) void k1_gemm(const float* __restrict__ q,
                                               const float* __restrict__ W,
                                               float* __restrict__ gpart) {
    __shared__ float qs[64][65];
    __shared__ float wsm[64][65];
    const int o0 = blockIdx.x * 64;
    const int k0 = blockIdx.y * 128;
    const int tid = threadIdx.x;
    const int ty = tid >> 4, tx = tid & 15;

    float acc[4][4];
#pragma unroll
    for (int i = 0; i < 4; ++i)
#pragma unroll
        for (int j = 0; j < 4; ++j) acc[i][j] = 0.f;

    for (int kc = 0; kc < 128; kc += 64) {
#pragma unroll
        for (int r = 0; r < 4; ++r) {
            int idx = tid + r * 256;
            int row = idx >> 4;
            int c4 = (idx & 15) << 2;
            float4 vq = *(const float4*)&q[row * Qn + k0 + kc + c4];
            qs[row][c4 + 0] = vq.x; qs[row][c4 + 1] = vq.y;
            qs[row][c4 + 2] = vq.z; qs[row][c4 + 3] = vq.w;
            float4 vw = *(const float4*)&W[(o0 + row) * Qn + k0 + kc + c4];
            wsm[row][c4 + 0] = vw.x; wsm[row][c4 + 1] = vw.y;
            wsm[row][c4 + 2] = vw.z; wsm[row][c4 + 3] = vw.w;
        }
        __syncthreads();
#pragma unroll 8
        for (int kk = 0; kk < 64; ++kk) {
            float aa[4], bb[4];
#pragma unroll
            for (int i = 0; i < 4; ++i) aa[i] = qs[ty * 4 + i][kk];
#pragma unroll
            for (int j = 0; j < 4; ++j) bb[j] = wsm[tx * 4 + j][kk];
#pragma unroll
            for (int i = 0; i < 4; ++i)
#pragma unroll
                for (int j = 0; j < 4; ++j) acc[i][j] += aa[i] * bb[j];
        }
        __syncthreads();
    }
#pragma unroll
    for (int i = 0; i < 4; ++i) {
        float4 w4 = make_float4(acc[i][0], acc[i][1], acc[i][2], acc[i][3]);
        *(float4*)&gpart[(blockIdx.y * 64 + ty * 4 + i) * NO + o0 + tx * 4] = w4;
    }
}

// ---------------- K1b: reduce k-splits + bias, transpose to kern[w][b][c]
__global__ __launch_bounds__(256) void k1b_reduce(const float* __restrict__ gpart,
                                                  const float* __restrict__ bias,
                                                  float* __restrict__ kern) {
    int idx = blockIdx.x * 256 + threadIdx.x;
    if (idx >= 3 * Bn * Cn) return;
    int w = idx / (Bn * Cn);
    int rem = idx - w * (Bn * Cn);
    int b = rem >> 9;
    int c = rem & 511;
    int o = c * 3 + w;
    float s = bias[o];
#pragma unroll
    for (int ks = 0; ks < 4; ++ks) s += gpart[(ks * Bn + b) * NO + o];
    kern[idx] = s;
}

// ---------------- K2: fused 3-tap conv-dot, sliding window. wave = (b, 32 t's)
// aBT[b][t] = k[t-1]·kern0 + k[t]·kern1 + k[t+1]·kern2 (edge rows dropped)
__global__ __launch_bounds__(256) void k2_dots(const float* __restrict__ kin,
                                               const float* __restrict__ kern,
                                               float* __restrict__ aBT) {
    const int wid = (blockIdx.x << 2) + (threadIdx.x >> 6);
    const int lane = threadIdx.x & 63;
    const int b = wid & 63;
    const int t0 = (wid >> 6) << 5;   // 32 t per wave

    // kern fragments: lane owns c = lane*4..+3 and 256+lane*4..+3
    f4 kwA[3], kwB[3];
#pragma unroll
    for (int w = 0; w < 3; ++w) {
        const f4* p = (const f4*)(kern + (w * Bn + b) * Cn);
        kwA[w] = p[lane];
        kwB[w] = p[64 + lane];
    }

    float al[32];
#pragma unroll
    for (int j = 0; j < 32; ++j) al[j] = 0.f;

    if (t0 > 0) {
        const f4* kr = (const f4*)(kin + ((size_t)(t0 - 1) * Bn + b) * Cn);
        f4 a = kr[lane], c = kr[64 + lane];
        al[0] += dot8(a, c, kwA[0], kwB[0]);     // kern0 * k[t0-1] -> a(t0)
    }
#pragma unroll
    for (int j = 0; j < 32; ++j) {
        const int t = t0 + j;
        const f4* kr = (const f4*)(kin + ((size_t)t * Bn + b) * Cn);
        f4 a = kr[lane], c = kr[64 + lane];
        if (j + 1 < 32) al[j + 1] += dot8(a, c, kwA[0], kwB[0]);  // -> a(t+1)
        al[j] += dot8(a, c, kwA[1], kwB[1]);                      // -> a(t)
        if (j >= 1) al[j - 1] += dot8(a, c, kwA[2], kwB[2]);      // -> a(t-1)
    }
    if (t0 + 32 < Ln) {
        const f4* kr = (const f4*)(kin + ((size_t)(t0 + 32) * Bn + b) * Cn);
        f4 a = kr[lane], c = kr[64 + lane];
        al[31] += dot8(a, c, kwA[2], kwB[2]);    // kern2 * k[t0+32] -> a(t0+31)
    }

    // 32 independent butterfly reductions
#pragma unroll
    for (int j = 0; j < 32; ++j) {
        float s = al[j];
#pragma unroll
        for (int off = 32; off; off >>= 1) s += __shfl_xor(s, off);
        al[j] = s;
    }
    if (lane == 0) {
        float* dst = aBT + b * Ln + t0;
#pragma unroll
        for (int j = 0; j < 8; ++j) {
            f4 o;
            o.x = al[4 * j]; o.y = al[4 * j + 1]; o.z = al[4 * j + 2]; o.w = al[4 * j + 3];
            *(f4*)&dst[4 * j] = o;
        }
    }
}

// ---------------- K3a: per-b masked softmax stats (mx, 1/sum)
__global__ __launch_bounds__(256) void k3a_stats(const float* __restrict__ aBT,
                                                 const int* __restrict__ kmask,
                                                 float* __restrict__ stats) {
    const int b = blockIdx.x;
    const int tid = threadIdx.x;
    const f4* arow = (const f4*)(aBT + b * Ln);

    f4 x[2];
    x[0] = arow[tid];
    x[1] = arow[256 + tid];
    int m[8];
    float av[8];
    float lmax = -FLT_MAX;
#pragma unroll
    for (int h = 0; h < 2; ++h)
#pragma unroll
        for (int i = 0; i < 4; ++i) {
            int t = h * 1024 + tid * 4 + i;
            float val = x[h][i];
            av[h * 4 + i] = val;
            m[h * 4 + i] = kmask[t * Bn + b];
            if (m[h * 4 + i]) lmax = fmaxf(lmax, val);
        }
    __shared__ float red[4];
#pragma unroll
    for (int off = 32; off; off >>= 1) lmax = fmaxf(lmax, __shfl_xor(lmax, off));
    if ((tid & 63) == 0) red[tid >> 6] = lmax;
    __syncthreads();
    const float mx = fmaxf(fmaxf(red[0], red[1]), fmaxf(red[2], red[3]));
    __syncthreads();
    float lsum = 0.f;
#pragma unroll
    for (int i = 0; i < 8; ++i) lsum += m[i] ? __expf(av[i] - mx) : 0.f;
#pragma unroll
    for (int off = 32; off; off >>= 1) lsum += __shfl_xor(lsum, off);
    if ((tid & 63) == 0) red[tid >> 6] = lsum;
    __syncthreads();
    if (tid == 0) {
        float s = red[0] + red[1] + red[2] + red[3];
        stats[2 * b] = mx;
        stats[2 * b + 1] = 1.f / s;
    }
}

// ---------------- K3b: emit a/e in [t][b] layout via LDS transpose + eT[b][t]
__global__ __launch_bounds__(256) void k3b_emit(const float* __restrict__ aBT,
                                                const int* __restrict__ kmask,
                                                const float* __restrict__ stats,
                                                float* __restrict__ out_a,
                                                float* __restrict__ out_e,
                                                float* __restrict__ eT) {
    __shared__ float lsa[64][65];
    __shared__ float lse[64][65];
    const int t0 = blockIdx.x * 64;
    const int tid = threadIdx.x;
    const int r = tid >> 4;      // 0..15
    const int c4 = tid & 15;     // f4 column

    // pass 1: b-major read, compute e, write eT, stash tiles
#pragma unroll
    for (int p = 0; p < 4; ++p) {
        const int b = p * 16 + r;
        const float mx = stats[2 * b];
        const float inv = stats[2 * b + 1];
        f4 av = *(const f4*)&aBT[b * Ln + t0 + c4 * 4];
        f4 ev;
#pragma unroll
        for (int i = 0; i < 4; ++i) {
            int t = t0 + c4 * 4 + i;
            int m = kmask[t * Bn + b];
            ev[i] = m ? __expf(av[i] - mx) * inv : 0.f;
            lsa[b][c4 * 4 + i] = av[i];
            lse[b][c4 * 4 + i] = ev[i];
        }
        *(f4*)&eT[b * Ln + t0 + c4 * 4] = ev;
    }
    __syncthreads();
    // pass 2: t-major write (full 256B lines)
#pragma unroll
    for (int p = 0; p < 4; ++p) {
        const int t = p * 16 + r;
        f4 oa, oe;
#pragma unroll
        for (int i = 0; i < 4; ++i) {
            oa[i] = lsa[c4 * 4 + i][t];
            oe[i] = lse[c4 * 4 + i][t];
        }
        *(f4*)&out_a[(t0 + t) * Bn + c4 * 4] = oa;
        *(f4*)&out_e[(t0 + t) * Bn + c4 * 4] = oe;
    }
}

// ---------------- K4: sparse PV partials via ballot-skip. block = (t-chunk 256) x b
__global__ __launch_bounds__(256) void k4_pv(const float* __restrict__ v,
                                             const float* __restrict__ eT,
                                             float* __restrict__ vpart) {
    const int c = blockIdx.x >> 6;    // 0..7
    const int b = blockIdx.x & 63;
    const int tid = threadIdx.x;

    __shared__ float es[256];
    __shared__ unsigned long long bm[4];
    const float e = eT[b * Ln + c * 256 + tid];
    es[tid] = e;
    unsigned long long bal = __ballot(e != 0.f);
    if ((tid & 63) == 0) bm[tid >> 6] = bal;
    __syncthreads();

    f2 acc;
    acc.x = 0.f;
    acc.y = 0.f;
#pragma unroll
    for (int w = 0; w < 4; ++w) {
        unsigned long long mm = bm[w];
        while (mm) {
            int bit = __ffsll((unsigned long long)mm) - 1;
            mm &= mm - 1;
            int tt = w * 64 + bit;
            float ee = es[tt];
            const f2* vrow = (const f2*)(v + (((size_t)(c * 256 + tt) * Bn + b) << 9));
            f2 vv = __builtin_nontemporal_load(vrow + tid);
            acc.x += ee * vv.x;
            acc.y += ee * vv.y;
        }
    }
    *(f2*)&vpart[((c * Bn + b) << 9) + tid * 2] = acc;
}

// ---------------- K5: reduce v partials -> attend[b, v]
__global__ __launch_bounds__(256) void k5_reduce(const float* __restrict__ vpart,
                                                 float* __restrict__ out_att) {
    const int idx = blockIdx.x * 256 + threadIdx.x;  // [0, 32768)
    float s = 0.f;
#pragma unroll
    for (int c = 0; c < 8; ++c) s += vpart[c * (Bn * Vn) + idx];
    out_att[idx] = s;
}

extern "C" void kernel_launch(void* const* d_in, const int* in_sizes, int n_in,
                              void* d_out, int out_size, void* d_ws, size_t ws_size,
                              hipStream_t stream) {
    const float* q = (const float*)d_in[0];
    const float* k = (const float*)d_in[1];
    const float* v = (const float*)d_in[2];
    const int* kmask = (const int*)d_in[3];
    const float* W = (const float*)d_in[4];
    const float* bias = (const float*)d_in[5];

    float* out = (float*)d_out;
    float* out_a = out;                      // [L, B]
    float* out_e = out + Ln * Bn;            // [L, B]
    float* out_att = out + 2 * Ln * Bn;      // [B, V]

    float* ws = (float*)d_ws;
    float* kern = ws + OFF_KERN;
    float* aBT = ws + OFF_ABT;
    float* eT = ws + OFF_ET;
    float* stats = ws + OFF_STAT;
    float* scr = ws + OFF_SCR;   // gemm partials, later v partials (disjoint phases)

    k1_gemm<<<dim3(24, 4), 256, 0, stream>>>(q, W, scr);
    k1b_reduce<<<(3 * Bn * Cn + 255) / 256, 256, 0, stream>>>(scr, bias, kern);
    k2_dots<<<1024, 256, 0, stream>>>(k, kern, aBT);
    k3a_stats<<<Bn, 256, 0, stream>>>(aBT, kmask, stats);
    k3b_emit<<<Ln / 64, 256, 0, stream>>>(aBT, kmask, stats, out_a, out_e, eT);
    k4_pv<<<8 * Bn, 256, 0, stream>>>(v, eT, scr);
    k5_reduce<<<(Bn * Vn) / 256, 256, 0, stream>>>(scr, out_att);
}